// Round 2
// baseline (982.838 us; speedup 1.0000x reference)
//
#include <hip/hip_runtime.h>

#define T_LEN 2048
#define B_SZ  64
#define I_DIM 128
#define H_DIM 256

typedef _Float16 f16;
typedef _Float16 f16x8 __attribute__((ext_vector_type(8)));
typedef float    f32x4 __attribute__((ext_vector_type(4)));

__device__ __forceinline__ float fast_sigmoid(float z) {
  return __builtin_amdgcn_rcpf(1.0f + __expf(-z));
}

// Raw barrier: orders LDS (lgkmcnt(0)) but leaves global prefetch loads in
// flight across the barrier (no vmcnt drain, unlike __syncthreads).
#define WG_BARRIER() do {                                  \
  asm volatile("s_waitcnt lgkmcnt(0)" ::: "memory");       \
  __builtin_amdgcn_s_barrier();                            \
  asm volatile("" ::: "memory");                           \
  __builtin_amdgcn_sched_barrier(0);                       \
} while (0)

// ---------------------------------------------------------------------------
// Kernel 1: xproj[t][b][:] = x[b][t][:] @ Wx + bias   (written into d_out)
// grid (16, 64): blockIdx.x = 128-t chunk, blockIdx.y = b. 256 thr = 4 waves.
// Wave w owns cols [64w, 64w+64).
// ---------------------------------------------------------------------------
__global__ __launch_bounds__(256) void xproj_kernel(
    const float* __restrict__ x, const float* __restrict__ W,
    const float* __restrict__ bias, float* __restrict__ out) {
  const int b    = blockIdx.y;
  const int tc   = blockIdx.x * 128;
  const int w    = threadIdx.x >> 6;
  const int lane = threadIdx.x & 63;
  const int cl   = lane & 15;
  const int kh   = lane >> 4;

  // Wx fragments: B[k][c], c = 64w+16g+cl, k = 32q+8kh+j (8 consecutive k/lane)
  f16x8 Bf[4][4];
#pragma unroll
  for (int g = 0; g < 4; ++g) {
    const int c = 64 * w + 16 * g + cl;
#pragma unroll
    for (int q = 0; q < 4; ++q)
#pragma unroll
      for (int j = 0; j < 8; ++j)
        Bf[g][q][j] = (f16)W[(32 * q + 8 * kh + j) * H_DIM + c];
  }
  float bv[4];
#pragma unroll
  for (int g = 0; g < 4; ++g) bv[g] = bias[64 * w + 16 * g + cl];

#pragma unroll 1
  for (int tb = 0; tb < 128; tb += 16) {
    const int t0 = tc + tb;
    // A fragments: A[r][k] = x[b][t0+r][k], r = cl, k = 8kh+j+32q
    const float* xrow = x + ((size_t)b * T_LEN + (t0 + cl)) * I_DIM + 8 * kh;
    f16x8 Af[4];
#pragma unroll
    for (int q = 0; q < 4; ++q) {
      float4 u0 = *(const float4*)(xrow + 32 * q);
      float4 u1 = *(const float4*)(xrow + 32 * q + 4);
      f16x8 a;
      a[0] = (f16)u0.x; a[1] = (f16)u0.y; a[2] = (f16)u0.z; a[3] = (f16)u0.w;
      a[4] = (f16)u1.x; a[5] = (f16)u1.y; a[6] = (f16)u1.z; a[7] = (f16)u1.w;
      Af[q] = a;
    }
#pragma unroll
    for (int g = 0; g < 4; ++g) {
      f32x4 acc = {0.f, 0.f, 0.f, 0.f};
#pragma unroll
      for (int q = 0; q < 4; ++q)
        acc = __builtin_amdgcn_mfma_f32_16x16x32_f16(Af[q], Bf[g][q], acc, 0, 0, 0);
      // D: row = 4kh+j, col = cl (+16g+64w)
#pragma unroll
      for (int j = 0; j < 4; ++j) {
        const int t = t0 + 4 * kh + j;
        out[((size_t)t * B_SZ + b) * H_DIM + 64 * w + 16 * g + cl] = acc[j] + bv[g];
      }
    }
  }
}

// ---------------------------------------------------------------------------
// Kernel 2: sequential scan. One workgroup per batch row b. 512 thr = 8 waves,
// wave w owns output cols [32w, 32w+32) with Wh fragments VGPR-resident.
//
// Broadcast-A trick: ALL 16 rows of the A-tile hold h (all 64 lanes read the
// same 4 LDS addresses per q — pure broadcast, no conflicts, no divergence).
// Every row of D then equals z, so each lane locally holds z for both of its
// column groups: no cross-lane shuffle is needed before the sigmoid.
// h exchange via a 2x512B double-buffered LDS row; xp read in-place from
// d_out (kernel 1's output) with a 4-step register prefetch; h_t overwrites
// the same row after the barrier (store overlaps next step's ds_read latency).
// ---------------------------------------------------------------------------
#define RNN_STEP(tt, pp, RB) do {                                            \
  f16x8 Af[8];                                                               \
  _Pragma("unroll")                                                          \
  for (int q = 0; q < 8; ++q)                                                \
    Af[q] = *(const f16x8*)&hbuf[RB][32 * q + 8 * kh];                       \
  f32x4 a00 = {0.f, 0.f, 0.f, 0.f};                                          \
  f32x4 a01 = {0.f, 0.f, 0.f, 0.f};                                          \
  f32x4 a10 = {0.f, 0.f, 0.f, 0.f};                                          \
  f32x4 a11 = {0.f, 0.f, 0.f, 0.f};                                          \
  _Pragma("unroll")                                                          \
  for (int q = 0; q < 4; ++q) {                                              \
    a00 = __builtin_amdgcn_mfma_f32_16x16x32_f16(Af[q],     Bf[0][q],     a00, 0, 0, 0); \
    a10 = __builtin_amdgcn_mfma_f32_16x16x32_f16(Af[q],     Bf[1][q],     a10, 0, 0, 0); \
    a01 = __builtin_amdgcn_mfma_f32_16x16x32_f16(Af[q + 4], Bf[0][q + 4], a01, 0, 0, 0); \
    a11 = __builtin_amdgcn_mfma_f32_16x16x32_f16(Af[q + 4], Bf[1][q + 4], a11, 0, 0, 0); \
  }                                                                          \
  float zz = ((lane < 16) ? (a00[0] + a01[0]) : (a10[0] + a11[0])) + (pp);   \
  float hh = fast_sigmoid(zz);                                               \
  if (act) hbuf[(RB) ^ 1][colx] = (f16)hh;                                   \
  WG_BARRIER();                                                              \
  if (act) op[(size_t)(tt) * rowstride] = hh;                                \
} while (0)

__global__ __launch_bounds__(512) void rnn_kernel(
    const float* __restrict__ W, float* out) {
  const int b    = blockIdx.x;
  const int w    = threadIdx.x >> 6;
  const int lane = threadIdx.x & 63;
  const int cl   = lane & 15;
  const int kh   = lane >> 4;

  __shared__ __align__(16) f16 hbuf[2][H_DIM];
  if (threadIdx.x < H_DIM) {
    hbuf[0][threadIdx.x] = (f16)0.f;
    hbuf[1][threadIdx.x] = (f16)0.f;
  }

  // Wh fragments (persistent in VGPRs): B[k][c], c = 32w+16g+cl, k = 32q+8kh+j
  f16x8 Bf[2][8];
#pragma unroll
  for (int g = 0; g < 2; ++g) {
    const int c = 32 * w + 16 * g + cl;
#pragma unroll
    for (int q = 0; q < 8; ++q)
#pragma unroll
      for (int j = 0; j < 8; ++j)
        Bf[g][q][j] = (f16)W[(I_DIM + 32 * q + 8 * kh + j) * H_DIM + c];
  }

  const bool   act  = (lane < 32);
  const int    colx = 32 * w + (lane & 31);
  const size_t rowstride = (size_t)B_SZ * H_DIM;
  float* op = out + (size_t)b * H_DIM + colx;   // &out[(t*B + b)*H + colx] at t=0

  __syncthreads();

  // xp prefetch pipeline, depth 4
  float p0 = act ? op[0 * rowstride] : 0.f;
  float p1 = act ? op[1 * rowstride] : 0.f;
  float p2 = act ? op[2 * rowstride] : 0.f;
  float p3 = act ? op[3 * rowstride] : 0.f;

#pragma unroll 1
  for (int t = 0; t < T_LEN; t += 4) {
    float n0 = act ? op[(size_t)((t + 4 < T_LEN) ? t + 4 : T_LEN - 1) * rowstride] : 0.f;
    RNN_STEP(t + 0, p0, 0); p0 = n0;
    float n1 = act ? op[(size_t)((t + 5 < T_LEN) ? t + 5 : T_LEN - 1) * rowstride] : 0.f;
    RNN_STEP(t + 1, p1, 1); p1 = n1;
    float n2 = act ? op[(size_t)((t + 6 < T_LEN) ? t + 6 : T_LEN - 1) * rowstride] : 0.f;
    RNN_STEP(t + 2, p2, 0); p2 = n2;
    float n3 = act ? op[(size_t)((t + 7 < T_LEN) ? t + 7 : T_LEN - 1) * rowstride] : 0.f;
    RNN_STEP(t + 3, p3, 1); p3 = n3;
  }
}

extern "C" void kernel_launch(void* const* d_in, const int* in_sizes, int n_in,
                              void* d_out, int out_size, void* d_ws, size_t ws_size,
                              hipStream_t stream) {
  (void)in_sizes; (void)n_in; (void)d_ws; (void)ws_size; (void)out_size;
  const float* x    = (const float*)d_in[0];
  const float* W    = (const float*)d_in[1];
  const float* bias = (const float*)d_in[2];
  float* out = (float*)d_out;

  xproj_kernel<<<dim3(16, 64), 256, 0, stream>>>(x, W, bias, out);
  rnn_kernel<<<64, 512, 0, stream>>>(W, out);
}

// Round 4
// 977.500 us; speedup vs baseline: 1.0055x; 1.0055x over previous
//
#include <hip/hip_runtime.h>

#define T_LEN 2048
#define B_SZ  64
#define I_DIM 128
#define H_DIM 256

typedef _Float16 f16;
typedef _Float16 f16x8 __attribute__((ext_vector_type(8)));
typedef float    f32x4 __attribute__((ext_vector_type(4)));

__device__ __forceinline__ float fast_sigmoid(float z) {
  return __builtin_amdgcn_rcpf(1.0f + __expf(-z));
}

// Raw barrier: orders LDS (lgkmcnt(0)) but leaves global prefetch loads in
// flight across the barrier (no vmcnt drain, unlike __syncthreads).
#define WG_BARRIER() do {                                  \
  asm volatile("s_waitcnt lgkmcnt(0)" ::: "memory");       \
  __builtin_amdgcn_s_barrier();                            \
  asm volatile("" ::: "memory");                           \
  __builtin_amdgcn_sched_barrier(0);                       \
} while (0)

// ---------------------------------------------------------------------------
// Kernel 1: xproj[t][b][:] = x[b][t][:] @ Wx + bias   (written into d_out)
// grid (16, 64): blockIdx.x = 128-t chunk, blockIdx.y = b. 256 thr = 4 waves.
// Wave w owns cols [64w, 64w+64).
// ---------------------------------------------------------------------------
__global__ __launch_bounds__(256) void xproj_kernel(
    const float* __restrict__ x, const float* __restrict__ W,
    const float* __restrict__ bias, float* __restrict__ out) {
  const int b    = blockIdx.y;
  const int tc   = blockIdx.x * 128;
  const int w    = threadIdx.x >> 6;
  const int lane = threadIdx.x & 63;
  const int cl   = lane & 15;
  const int kh   = lane >> 4;

  // Wx fragments: B[k][c], c = 64w+16g+cl, k = 32q+8kh+j (8 consecutive k/lane)
  f16x8 Bf[4][4];
#pragma unroll
  for (int g = 0; g < 4; ++g) {
    const int c = 64 * w + 16 * g + cl;
#pragma unroll
    for (int q = 0; q < 4; ++q)
#pragma unroll
      for (int j = 0; j < 8; ++j)
        Bf[g][q][j] = (f16)W[(32 * q + 8 * kh + j) * H_DIM + c];
  }
  float bv[4];
#pragma unroll
  for (int g = 0; g < 4; ++g) bv[g] = bias[64 * w + 16 * g + cl];

#pragma unroll 1
  for (int tb = 0; tb < 128; tb += 16) {
    const int t0 = tc + tb;
    // A fragments: A[r][k] = x[b][t0+r][k], r = cl, k = 8kh+j+32q
    const float* xrow = x + ((size_t)b * T_LEN + (t0 + cl)) * I_DIM + 8 * kh;
    f16x8 Af[4];
#pragma unroll
    for (int q = 0; q < 4; ++q) {
      float4 u0 = *(const float4*)(xrow + 32 * q);
      float4 u1 = *(const float4*)(xrow + 32 * q + 4);
      f16x8 a;
      a[0] = (f16)u0.x; a[1] = (f16)u0.y; a[2] = (f16)u0.z; a[3] = (f16)u0.w;
      a[4] = (f16)u1.x; a[5] = (f16)u1.y; a[6] = (f16)u1.z; a[7] = (f16)u1.w;
      Af[q] = a;
    }
#pragma unroll
    for (int g = 0; g < 4; ++g) {
      f32x4 acc = {0.f, 0.f, 0.f, 0.f};
#pragma unroll
      for (int q = 0; q < 4; ++q)
        acc = __builtin_amdgcn_mfma_f32_16x16x32_f16(Af[q], Bf[g][q], acc, 0, 0, 0);
      // D: row = 4kh+j, col = cl (+16g+64w)
#pragma unroll
      for (int j = 0; j < 4; ++j) {
        const int t = t0 + 4 * kh + j;
        out[((size_t)t * B_SZ + b) * H_DIM + 64 * w + 16 * g + cl] = acc[j] + bv[g];
      }
    }
  }
}

// ---------------------------------------------------------------------------
// Kernel 2: sequential scan. One workgroup per batch row b. 1024 thr = 16
// waves; wave w owns output cols [16w, 16w+16) — exactly ONE 16x16 D-tile,
// so its z (D row 0) lives in its own lanes 0-15: no cross-lane move at all.
// Wh fragments VGPR-resident (8 x f16x8 per wave). Only the 4 lanes with
// (lane&15)==0 re-read A fragments each step (M-tile rows 1..15 stay zero).
// h exchange via 2x512B double-buffered LDS row; xp read in-place from d_out
// (kernel 1's output) with a 4-step register prefetch; h_t overwrites the
// same row after the barrier (store overlaps next step's ds_read latency).
// ---------------------------------------------------------------------------
#define MFMA16(A, B, C) __builtin_amdgcn_mfma_f32_16x16x32_f16((A), (B), (C), 0, 0, 0)

#define RNN_STEP(tt, pp, RB) do {                                            \
  if (cl == 0) {                                                             \
    _Pragma("unroll")                                                        \
    for (int q = 0; q < 8; ++q)                                              \
      Af[q] = *(const f16x8*)&hbuf[RB][32 * q + 8 * kh];                     \
  }                                                                          \
  f32x4 a0 = MFMA16(Af[0], Bf[0], Zacc);                                     \
  f32x4 a1 = MFMA16(Af[4], Bf[4], Zacc);                                     \
  _Pragma("unroll")                                                          \
  for (int q = 1; q < 4; ++q) {                                              \
    a0 = MFMA16(Af[q],     Bf[q],     a0);                                   \
    a1 = MFMA16(Af[q + 4], Bf[q + 4], a1);                                   \
  }                                                                          \
  float hh = fast_sigmoid(a0[0] + a1[0] + (pp));                             \
  if (act) hbuf[(RB) ^ 1][colx] = (f16)hh;                                   \
  WG_BARRIER();                                                              \
  if (act) op[(size_t)(tt) * rowstride] = hh;                                \
} while (0)

__global__ __launch_bounds__(1024) void rnn_kernel(
    const float* __restrict__ W, float* out) {
  const int b    = blockIdx.x;
  const int w    = threadIdx.x >> 6;
  const int lane = threadIdx.x & 63;
  const int cl   = lane & 15;
  const int kh   = lane >> 4;

  __shared__ __align__(16) f16 hbuf[2][H_DIM];
  if (threadIdx.x < H_DIM) {
    hbuf[0][threadIdx.x] = (f16)0.f;
    hbuf[1][threadIdx.x] = (f16)0.f;
  }

  // Wh fragment (persistent in VGPRs): B[k][c], c = 16w+cl, k = 32q+8kh+j
  f16x8 Bf[8];
  {
    const int c = 16 * w + cl;
#pragma unroll
    for (int q = 0; q < 8; ++q)
#pragma unroll
      for (int j = 0; j < 8; ++j)
        Bf[q][j] = (f16)W[(I_DIM + 32 * q + 8 * kh + j) * H_DIM + c];
  }

  // A fragments: rows 1..15 stay zero forever (only 4 lanes/wave load row 0)
  f16x8 Af[8];
#pragma unroll
  for (int q = 0; q < 8; ++q)
#pragma unroll
    for (int j = 0; j < 8; ++j) Af[q][j] = (f16)0.f;

  // Loop-invariant zero accumulator (C-operand of the first MFMA of each
  // chain) — avoids per-step v_accvgpr_write zero-init of the accumulators.
  const f32x4 Zacc = {0.f, 0.f, 0.f, 0.f};

  const bool   act  = (lane < 16);
  const int    colx = 16 * w + cl;
  const size_t rowstride = (size_t)B_SZ * H_DIM;
  // All lanes compute an address (lanes 16-63 duplicate lanes 0-15) so the
  // xp prefetch needs no exec-mask ternaries; only stores are act-guarded.
  float* op = out + (size_t)b * H_DIM + colx;   // &out[(t*B + b)*H + colx] at t=0

  __syncthreads();

  // xp prefetch pipeline, depth 4
  float p0 = op[0 * rowstride];
  float p1 = op[1 * rowstride];
  float p2 = op[2 * rowstride];
  float p3 = op[3 * rowstride];

#pragma unroll 1
  for (int t = 0; t < T_LEN; t += 4) {
    float n0 = op[(size_t)((t + 4 < T_LEN) ? t + 4 : T_LEN - 1) * rowstride];
    RNN_STEP(t + 0, p0, 0); p0 = n0;
    float n1 = op[(size_t)((t + 5 < T_LEN) ? t + 5 : T_LEN - 1) * rowstride];
    RNN_STEP(t + 1, p1, 1); p1 = n1;
    float n2 = op[(size_t)((t + 6 < T_LEN) ? t + 6 : T_LEN - 1) * rowstride];
    RNN_STEP(t + 2, p2, 0); p2 = n2;
    float n3 = op[(size_t)((t + 7 < T_LEN) ? t + 7 : T_LEN - 1) * rowstride];
    RNN_STEP(t + 3, p3, 1); p3 = n3;
  }
}

extern "C" void kernel_launch(void* const* d_in, const int* in_sizes, int n_in,
                              void* d_out, int out_size, void* d_ws, size_t ws_size,
                              hipStream_t stream) {
  (void)in_sizes; (void)n_in; (void)d_ws; (void)ws_size; (void)out_size;
  const float* x    = (const float*)d_in[0];
  const float* W    = (const float*)d_in[1];
  const float* bias = (const float*)d_in[2];
  float* out = (float*)d_out;

  xproj_kernel<<<dim3(16, 64), 256, 0, stream>>>(x, W, bias, out);
  rnn_kernel<<<64, 1024, 0, stream>>>(W, out);
}

// Round 5
// 899.371 us; speedup vs baseline: 1.0928x; 1.0869x over previous
//
#include <hip/hip_runtime.h>

#define T_LEN 2048
#define B_SZ  64
#define I_DIM 128
#define H_DIM 256

typedef _Float16 f16;
typedef _Float16 f16x8 __attribute__((ext_vector_type(8)));
typedef float    f32x4 __attribute__((ext_vector_type(4)));

__device__ __forceinline__ float fast_sigmoid(float z) {
  return __builtin_amdgcn_rcpf(1.0f + __expf(-z));
}

// Raw barrier: orders LDS (lgkmcnt(0)) but leaves global prefetch loads in
// flight across the barrier (no vmcnt drain, unlike __syncthreads).
#define WG_BARRIER() do {                                  \
  asm volatile("s_waitcnt lgkmcnt(0)" ::: "memory");       \
  __builtin_amdgcn_s_barrier();                            \
  asm volatile("" ::: "memory");                           \
  __builtin_amdgcn_sched_barrier(0);                       \
} while (0)

// ---------------------------------------------------------------------------
// Kernel 1: xproj[t][b][:] = x[b][t][:] @ Wx + bias   (written into d_out)
// grid (16, 64): blockIdx.x = 128-t chunk, blockIdx.y = b. 256 thr = 4 waves.
// Wave w owns cols [64w, 64w+64).
// ---------------------------------------------------------------------------
__global__ __launch_bounds__(256) void xproj_kernel(
    const float* __restrict__ x, const float* __restrict__ W,
    const float* __restrict__ bias, float* __restrict__ out) {
  const int b    = blockIdx.y;
  const int tc   = blockIdx.x * 128;
  const int w    = threadIdx.x >> 6;
  const int lane = threadIdx.x & 63;
  const int cl   = lane & 15;
  const int kh   = lane >> 4;

  // Wx fragments: B[k][c], c = 64w+16g+cl, k = 32q+8kh+j (8 consecutive k/lane)
  f16x8 Bf[4][4];
#pragma unroll
  for (int g = 0; g < 4; ++g) {
    const int c = 64 * w + 16 * g + cl;
#pragma unroll
    for (int q = 0; q < 4; ++q)
#pragma unroll
      for (int j = 0; j < 8; ++j)
        Bf[g][q][j] = (f16)W[(32 * q + 8 * kh + j) * H_DIM + c];
  }
  float bv[4];
#pragma unroll
  for (int g = 0; g < 4; ++g) bv[g] = bias[64 * w + 16 * g + cl];

#pragma unroll 1
  for (int tb = 0; tb < 128; tb += 16) {
    const int t0 = tc + tb;
    // A fragments: A[r][k] = x[b][t0+r][k], r = cl, k = 8kh+j+32q
    const float* xrow = x + ((size_t)b * T_LEN + (t0 + cl)) * I_DIM + 8 * kh;
    f16x8 Af[4];
#pragma unroll
    for (int q = 0; q < 4; ++q) {
      float4 u0 = *(const float4*)(xrow + 32 * q);
      float4 u1 = *(const float4*)(xrow + 32 * q + 4);
      f16x8 a;
      a[0] = (f16)u0.x; a[1] = (f16)u0.y; a[2] = (f16)u0.z; a[3] = (f16)u0.w;
      a[4] = (f16)u1.x; a[5] = (f16)u1.y; a[6] = (f16)u1.z; a[7] = (f16)u1.w;
      Af[q] = a;
    }
#pragma unroll
    for (int g = 0; g < 4; ++g) {
      f32x4 acc = {0.f, 0.f, 0.f, 0.f};
#pragma unroll
      for (int q = 0; q < 4; ++q)
        acc = __builtin_amdgcn_mfma_f32_16x16x32_f16(Af[q], Bf[g][q], acc, 0, 0, 0);
      // D: row = 4kh+j, col = cl (+16g+64w)
#pragma unroll
      for (int j = 0; j < 4; ++j) {
        const int t = t0 + 4 * kh + j;
        out[((size_t)t * B_SZ + b) * H_DIM + 64 * w + 16 * g + cl] = acc[j] + bv[g];
      }
    }
  }
}

// ---------------------------------------------------------------------------
// Kernel 2: sequential scan. One workgroup per batch row b. 256 thr = 4 waves
// (1 wave/SIMD); wave w owns output cols [64w, 64w+64) via 4 B-tiles.
//
// Multi-row shared-A trick: h is loaded into A-rows {0,4,8,12} of ONE
// fragment set (rows live in disjoint lanes cl in {0,4,8,12}, so a single
// 32-VGPR Af holds all four copies). All 4 tiles' MFMAs share Af; tile g's
// z appears in D-row 4g = lanes 16g..16g+15, reg 0. Hence lane l holds z for
// its own column 64w+l after 3 cndmasks — zero cross-lane ops, and only
// 8 ds_read_b128 per wave per step (32/CU, conflict-free 16-lane broadcast).
// Every lane produces one h: unguarded sigmoid, contiguous 128B ds_write,
// fully-coalesced 256B xp loads + h stores (post-barrier, off the spine).
// ---------------------------------------------------------------------------
#define MFMA16(A, B, C) __builtin_amdgcn_mfma_f32_16x16x32_f16((A), (B), (C), 0, 0, 0)

#define RNN_STEP(tt, pp, RB) do {                                            \
  if ((cl & 3) == 0) {                                                       \
    _Pragma("unroll")                                                        \
    for (int q = 0; q < 8; ++q)                                              \
      Af[q] = *(const f16x8*)&hbuf[RB][32 * q + 8 * kh];                     \
  }                                                                          \
  f32x4 a0 = MFMA16(Af[0], Bf[0][0], Zacc);                                  \
  f32x4 a1 = MFMA16(Af[0], Bf[1][0], Zacc);                                  \
  f32x4 a2 = MFMA16(Af[0], Bf[2][0], Zacc);                                  \
  f32x4 a3 = MFMA16(Af[0], Bf[3][0], Zacc);                                  \
  _Pragma("unroll")                                                          \
  for (int q = 1; q < 8; ++q) {                                              \
    a0 = MFMA16(Af[q], Bf[0][q], a0);                                        \
    a1 = MFMA16(Af[q], Bf[1][q], a1);                                        \
    a2 = MFMA16(Af[q], Bf[2][q], a2);                                        \
    a3 = MFMA16(Af[q], Bf[3][q], a3);                                        \
  }                                                                          \
  float zsel = g1 ? a1[0] : a0[0];                                           \
  zsel = g2 ? a2[0] : zsel;                                                  \
  zsel = g3 ? a3[0] : zsel;                                                  \
  float hh = fast_sigmoid(zsel + (pp));                                      \
  hbuf[(RB) ^ 1][colx] = (f16)hh;                                            \
  WG_BARRIER();                                                              \
  op[(size_t)(tt) * rowstride] = hh;                                         \
} while (0)

__global__ __launch_bounds__(256, 1) void rnn_kernel(
    const float* __restrict__ W, float* out) {
  const int b    = blockIdx.x;
  const int w    = threadIdx.x >> 6;
  const int lane = threadIdx.x & 63;
  const int cl   = lane & 15;
  const int kh   = lane >> 4;

  __shared__ __align__(16) f16 hbuf[2][H_DIM];
  hbuf[0][threadIdx.x] = (f16)0.f;
  hbuf[1][threadIdx.x] = (f16)0.f;

  // Wh fragments (persistent in VGPRs): tile g: B[k][c], c = 64w+16g+cl,
  // k = 32q+8kh+j. 4 tiles x 8 q x 4 VGPR = 128 VGPRs.
  f16x8 Bf[4][8];
#pragma unroll
  for (int g = 0; g < 4; ++g) {
    const int c = 64 * w + 16 * g + cl;
#pragma unroll
    for (int q = 0; q < 8; ++q)
#pragma unroll
      for (int j = 0; j < 8; ++j)
        Bf[g][q][j] = (f16)W[(I_DIM + 32 * q + 8 * kh + j) * H_DIM + c];
  }

  // Shared A fragments: rows {0,4,8,12} carry h (lanes cl in {0,4,8,12});
  // all other rows stay zero forever.
  f16x8 Af[8];
#pragma unroll
  for (int q = 0; q < 8; ++q)
#pragma unroll
    for (int j = 0; j < 8; ++j) Af[q][j] = (f16)0.f;

  // Loop-invariant zero accumulator (C-operand of the first MFMA of each
  // chain) — avoids per-step v_accvgpr_write zero-init of the accumulators.
  const f32x4 Zacc = {0.f, 0.f, 0.f, 0.f};

  // z-selection masks: lane group picks its tile's accumulator.
  const bool g1 = (lane >> 4) == 1;
  const bool g2 = (lane >> 4) == 2;
  const bool g3 = (lane >> 4) == 3;

  const int    colx = 64 * w + lane;       // this lane's output column
  const size_t rowstride = (size_t)B_SZ * H_DIM;
  float* op = out + (size_t)b * H_DIM + colx;   // &out[(t*B + b)*H + colx] at t=0

  __syncthreads();

  // xp prefetch pipeline, depth 4 (fully coalesced 256B per wave)
  float p0 = op[0 * rowstride];
  float p1 = op[1 * rowstride];
  float p2 = op[2 * rowstride];
  float p3 = op[3 * rowstride];

#pragma unroll 1
  for (int t = 0; t < T_LEN; t += 4) {
    float n0 = op[(size_t)((t + 4 < T_LEN) ? t + 4 : T_LEN - 1) * rowstride];
    RNN_STEP(t + 0, p0, 0); p0 = n0;
    float n1 = op[(size_t)((t + 5 < T_LEN) ? t + 5 : T_LEN - 1) * rowstride];
    RNN_STEP(t + 1, p1, 1); p1 = n1;
    float n2 = op[(size_t)((t + 6 < T_LEN) ? t + 6 : T_LEN - 1) * rowstride];
    RNN_STEP(t + 2, p2, 0); p2 = n2;
    float n3 = op[(size_t)((t + 7 < T_LEN) ? t + 7 : T_LEN - 1) * rowstride];
    RNN_STEP(t + 3, p3, 1); p3 = n3;
  }
}

extern "C" void kernel_launch(void* const* d_in, const int* in_sizes, int n_in,
                              void* d_out, int out_size, void* d_ws, size_t ws_size,
                              hipStream_t stream) {
  (void)in_sizes; (void)n_in; (void)d_ws; (void)ws_size; (void)out_size;
  const float* x    = (const float*)d_in[0];
  const float* W    = (const float*)d_in[1];
  const float* bias = (const float*)d_in[2];
  float* out = (float*)d_out;

  xproj_kernel<<<dim3(16, 64), 256, 0, stream>>>(x, W, bias, out);
  rnn_kernel<<<64, 256, 0, stream>>>(W, out);
}